// Round 4
// baseline (291.566 us; speedup 1.0000x reference)
//
#include <hip/hip_runtime.h>
#include <hip/hip_cooperative_groups.h>
#include <stdint.h>

namespace cg = cooperative_groups;

// Bert4Argument R11: out = seq·W1 (gathered K=768 GEMM)
//                        + pe_logits[l-pos+256]        (precomputed 528x208)
//                        + ce_logits[l==pos?frame:0]   (precomputed 208x208, bias folded)
// R10 -> R11: fuse prep (W-pack + logits) and gemm into ONE cooperative kernel
// (512 blocks x 512 thr = 2 blocks/CU co-resident, grid.sync between phases).
// Removes the prep dispatch + gap; prep work spread over the whole machine.
// Fallback to the two-dispatch R10 path if coop launch is rejected.

typedef __attribute__((ext_vector_type(8))) short short8;
typedef __attribute__((ext_vector_type(4))) float f32x4;

#define AS1 __attribute__((address_space(1)))
#define AS3 __attribute__((address_space(3)))

// ---- workspace layout ----
// Wp bf16, 13 tiles x [kb8 0..95][n16][8] = 159744 shorts (319488 B)
// pe_logits f32 [528][208] at float off 79872
// ce_logits f32 [208][208] at float off 189696 (bias folded)
#define TILE_STRIDE 12288     // shorts per n-tile (96*16*8)
#define NT         13
#define NPE_RT     33         // 33*16 = 528 rows cover 513
#define NCE_RT     13         // 13*16 = 208 rows cover 201
#define NLOG      ((NPE_RT + NCE_RT) * NT)   // 598 logits tiles
#define NPACK      19968      // pack thread-units
#define PEL_OFF_F  79872
#define CEL_OFF_F  189696
#define WS_NEED_B  931840
#define GRID       512

__device__ __forceinline__ unsigned short f2bf(float f) {
    union { float f; unsigned int u; } v; v.f = f;
    unsigned int u = v.u;
    return (unsigned short)((u + 0x7fffu + ((u >> 16) & 1u)) >> 16);
}

__device__ __forceinline__ short8 pack8(f32x4 a, f32x4 b) {
    short8 r;
    r[0] = (short)f2bf(a.x); r[1] = (short)f2bf(a.y);
    r[2] = (short)f2bf(a.z); r[3] = (short)f2bf(a.w);
    r[4] = (short)f2bf(b.x); r[5] = (short)f2bf(b.y);
    r[6] = (short)f2bf(b.z); r[7] = (short)f2bf(b.w);
    return r;
}

__device__ __forceinline__ void dma16(const unsigned short* g, AS3 unsigned short* l) {
    __builtin_amdgcn_global_load_lds((AS1 const unsigned int*)g,
                                     (AS3 unsigned int*)l, 16, 0, 0);
}

// ---------------------------------------------------------------------------
// W pack unit g: Wp[((t*96+kb8)*16+n)*8+j] = bf16(W[t*16+n][kb8*8+j]), rows>=200 zero
// ---------------------------------------------------------------------------
__device__ __forceinline__ void pack_unit(int g, const float* __restrict__ W,
                                          unsigned short* __restrict__ ws) {
    const int n   = g & 15;
    const int kb8 = (g >> 4) % 96;
    const int t   = g / 1536;
    const int row = t * 16 + n;
    const int col = kb8 * 8;
    f32x4 a = {0.f, 0.f, 0.f, 0.f}, b = {0.f, 0.f, 0.f, 0.f};
    if (row < 200) {
        const float* p = W + (size_t)row * 2304 + col;
        a = *(const f32x4*)p;
        b = *(const f32x4*)(p + 4);
    }
    *(short8*)(ws + (size_t)g * 8) = pack8(a, b);
}

// ---------------------------------------------------------------------------
// One logits tile bb (of NLOG): 16x16 output, 8 waves K-split 96 each,
// LDS tree reduce in red[2048] floats. Safe to call repeatedly (pre-guard sync).
// ---------------------------------------------------------------------------
__device__ void logits_tile(int bb,
                            const float* __restrict__ pe,
                            const float* __restrict__ ce,
                            const float* __restrict__ W,
                            const float* __restrict__ bias,
                            float* __restrict__ wsF,
                            float* red)
{
    const int w    = threadIdx.x >> 6;
    const int lane = threadIdx.x & 63;
    const int n16  = lane & 15;
    const int quad = lane >> 4;

    int rowtile, t, nrows, koff;
    const float* A;
    float* outL;
    bool isCe;
    if (bb < NPE_RT * NT) {
        isCe = false; rowtile = bb / NT; t = bb % NT;
        nrows = 513; koff = 768;  A = pe; outL = wsF + PEL_OFF_F;
    } else {
        const int b2 = bb - NPE_RT * NT;
        isCe = true;  rowtile = b2 / NT; t = b2 % NT;
        nrows = 201; koff = 1536; A = ce; outL = wsF + CEL_OFF_F;
    }

    int arow = rowtile * 16 + n16;
    if (arow >= nrows) arow = nrows - 1;            // clamped rows never written
    const float* abase = A + (size_t)arow * 768 + w * 96 + quad * 8;

    const int col  = t * 16 + n16;                  // cols >= 200 junk, never read
    const int wrow = (col < 200) ? col : 0;
    const float* wbase = W + (size_t)wrow * 2304 + koff + w * 96 + quad * 8;

    // all 12 loads issued before any use: one latency round-trip
    f32x4 av0[3], av1[3], wv0[3], wv1[3];
#pragma unroll
    for (int ks = 0; ks < 3; ++ks) {
        av0[ks] = *(const f32x4*)(abase + ks * 32);
        av1[ks] = *(const f32x4*)(abase + ks * 32 + 4);
        wv0[ks] = *(const f32x4*)(wbase + ks * 32);
        wv1[ks] = *(const f32x4*)(wbase + ks * 32 + 4);
    }
    f32x4 acc = (f32x4){0.f, 0.f, 0.f, 0.f};
#pragma unroll
    for (int ks = 0; ks < 3; ++ks)
        acc = __builtin_amdgcn_mfma_f32_16x16x32_bf16(
            pack8(av0[ks], av1[ks]), pack8(wv0[ks], wv1[ks]), acc, 0, 0, 0);

    __syncthreads();                 // guard: prior red readers done
#pragma unroll
    for (int r = 0; r < 4; ++r)
        red[w * 256 + lane * 4 + r] = acc[r];
    __syncthreads();
    if (threadIdx.x < 64) {
        const float bv = (isCe && col < 200) ? bias[col] : 0.0f;
#pragma unroll
        for (int r = 0; r < 4; ++r) {
            float s = 0.f;
#pragma unroll
            for (int ww = 0; ww < 8; ++ww)
                s += red[ww * 256 + lane * 4 + r];
            const int row = rowtile * 16 + quad * 4 + r;
            if (row < nrows)
                outL[(size_t)row * 208 + col] = s + bv;
        }
    }
}

// ---------------------------------------------------------------------------
// GEMM body: seq-part only, K=768 (6 chunks of 128). Block mblk = 32 rows x all
// 13 n-tiles. LDS 60 KB: A 8 slabs of 64x8 bf16; B 13 tiles x 2048 shorts.
// A: gathered f32 loads issued one chunk early, cvt->ds_write. B: dma16 from Wp.
// Epilogue: + pe_logits[rel,col] + ce_logits[cls,col] (bias inside), write f32.
// ---------------------------------------------------------------------------
__device__ void gemm_body(unsigned short* lds,
                          const unsigned short* __restrict__ ws,
                          const float* __restrict__ seq,
                          const int*   __restrict__ head,
                          const int*   __restrict__ frame,
                          const int*   __restrict__ pos,
                          float* __restrict__ out,
                          int mblk)
{
    const unsigned short* Wp = ws;
    const float* wsF = (const float*)ws;
    const float* peL = wsF + PEL_OFF_F;
    const float* ceL = wsF + CEL_OFF_F;

    const int tid  = threadIdx.x;
    const int wave = tid >> 6;
    const int lane = tid & 63;
    const int n16  = lane & 15;
    const int quad = lane >> 4;

    const int i       = mblk >> 3;
    const int pos_i   = pos[i];
    const int frame_i = frame[i];

    // ---- A staging: wave stages slab (sfm = wave&1, sk = wave>>1) ----
    const int sfm = wave & 1;
    const int sk  = wave >> 1;               // 0..3
    const int srow = mblk * 32 + sfm * 16 + n16;
    const int hi   = head[srow];
    const float* aP = seq + ((size_t)i * 256 + hi) * 768 + sk * 32 + quad * 8;
    unsigned short* aDst = lds + ((sfm * 4 + sk) * 64 + lane) * 8;

    // ---- compute partition: p = m-frag, q -> tiles q+4u ----
    const int p = wave & 1;
    const int q = wave >> 1;
    const unsigned short* aRd = lds + p * 2048 + lane * 8;
    const unsigned short* bRd[4];
    bool uok[4];
#pragma unroll
    for (int u = 0; u < 4; ++u) {
        const int t = q + 4 * u;
        uok[u] = (t < NT);
        bRd[u] = lds + 4096 + (uok[u] ? t : 0) * 2048 + quad * 128 + n16 * 8;
    }

    f32x4 acc[4];
#pragma unroll
    for (int u = 0; u < 4; ++u)
        acc[u] = (f32x4){0.f, 0.f, 0.f, 0.f};

    // prologue: issue A loads for chunk 0
    f32x4 a0 = *(const f32x4*)(aP);
    f32x4 a1 = *(const f32x4*)(aP + 4);

    for (int cc = 0; cc < 6; ++cc) {
        // stage A (regs -> LDS) and B (dma16: 52 units over 8 waves)
        *(short8*)aDst = pack8(a0, a1);
#pragma unroll
        for (int un = wave; un < 52; un += 8) {
            const int t = un >> 2, part = un & 3;
            dma16(Wp + (size_t)t * TILE_STRIDE + cc * 2048 + part * 512 + lane * 8,
                  (AS3 unsigned short*)lds + 4096 + t * 2048 + part * 512 + lane * 8);
        }
        __syncthreads();
        // issue next chunk's A loads after the drain: latency hides under MFMA
        if (cc < 5) {
            const float* ap = aP + (cc + 1) * 128;
            a0 = *(const f32x4*)(ap);
            a1 = *(const f32x4*)(ap + 4);
        }
#pragma unroll
        for (int ks = 0; ks < 4; ++ks) {
            short8 af = *(const short8*)(aRd + ks * 512);
#pragma unroll
            for (int u = 0; u < 4; ++u) {
                if (uok[u]) {
                    short8 bf = *(const short8*)(bRd[u] + ks * 512);
                    acc[u] = __builtin_amdgcn_mfma_f32_16x16x32_bf16(af, bf, acc[u], 0, 0, 0);
                }
            }
        }
        __syncthreads();
    }

    // epilogue: C/D col = lane&15, row = quad*4 + r; add gathered logits
    const int rbase = mblk * 32 + p * 16 + quad * 4;
#pragma unroll
    for (int u = 0; u < 4; ++u) {
        if (uok[u]) {
            const int col = (q + 4 * u) * 16 + n16;
            if (col < 200) {
#pragma unroll
                for (int r = 0; r < 4; ++r) {
                    const int row = rbase + r;
                    const int l   = row & 255;
                    const int rel = l - pos_i + 256;
                    const int cls = (l == pos_i) ? frame_i : 0;
                    out[(size_t)row * 200 + col] =
                        acc[u][r] + peL[(size_t)rel * 208 + col]
                                  + ceL[(size_t)cls * 208 + col];
                }
            }
        }
    }
}

// ---------------------------------------------------------------------------
// Fused cooperative kernel: phase 0 = pack + logits, grid.sync, phase 1 = gemm.
// ---------------------------------------------------------------------------
__global__ __launch_bounds__(512, 4) void fused_kernel(
    unsigned short* __restrict__ ws,
    const float* __restrict__ seq,
    const float* __restrict__ pe,
    const float* __restrict__ ce,
    const float* __restrict__ W,
    const float* __restrict__ bias,
    const int*   __restrict__ head,
    const int*   __restrict__ frame,
    const int*   __restrict__ pos,
    float* __restrict__ out)
{
    __shared__ unsigned short lds[4096 + 13 * 2048];   // 61440 B

    // ---- phase 0: prep ----
    {
        const int g = blockIdx.x * 512 + threadIdx.x;
        if (g < NPACK)
            pack_unit(g, W, ws);
        float* red = (float*)lds;
        logits_tile(blockIdx.x, pe, ce, W, bias, (float*)ws, red);
        if (blockIdx.x + GRID < NLOG)
            logits_tile(blockIdx.x + GRID, pe, ce, W, bias, (float*)ws, red);
    }
    __threadfence();
    cg::this_grid().sync();

    // ---- phase 1: gemm ----
    gemm_body(lds, ws, seq, head, frame, pos, out, blockIdx.x);
}

// ---------------------------------------------------------------------------
// Non-cooperative fallback pair (same math, two dispatches).
// ---------------------------------------------------------------------------
__global__ __launch_bounds__(512) void prep_kernel(
    const float* __restrict__ pe,
    const float* __restrict__ ce,
    const float* __restrict__ W,
    const float* __restrict__ bias,
    unsigned short* __restrict__ ws)
{
    __shared__ float red[2048];
    if (blockIdx.x < NLOG) {
        logits_tile(blockIdx.x, pe, ce, W, bias, (float*)ws, red);
    } else {
        const int g = (blockIdx.x - NLOG) * 512 + threadIdx.x;
        if (g < NPACK)
            pack_unit(g, W, ws);
    }
}

__global__ __launch_bounds__(512, 4) void gemm_kernel(
    const unsigned short* __restrict__ ws,
    const float* __restrict__ seq,
    const int*   __restrict__ head,
    const int*   __restrict__ frame,
    const int*   __restrict__ pos,
    float* __restrict__ out)
{
    __shared__ unsigned short lds[4096 + 13 * 2048];
    gemm_body(lds, ws, seq, head, frame, pos, out, blockIdx.x);
}

// ---------------------------------------------------------------------------
// Fallback (no workspace): slow but correct, f32 W converted inline.
// ---------------------------------------------------------------------------
__global__ __launch_bounds__(256) void gemm_fallback(
    const float* __restrict__ seq, const float* __restrict__ pe,
    const float* __restrict__ ce, const float* __restrict__ Wf,
    const float* __restrict__ bias, const int* __restrict__ head,
    const int* __restrict__ frame, const int* __restrict__ pos,
    float* __restrict__ out)
{
    const int tid  = threadIdx.x;
    const int wave = tid >> 6;
    const int lane = tid & 63;
    const int n16  = lane & 15;
    const int quad = lane >> 4;

    const int mrow  = blockIdx.x * 16 + n16;
    const int i     = mrow >> 8;
    const int j     = mrow & 255;
    const int pos_i = pos[i];
    const int hi    = head[mrow];
    const int rel   = j - pos_i + 256;
    const int cls   = (j == pos_i) ? frame[i] : 0;

    const float* segs[3];
    segs[0] = seq + ((size_t)i * 256 + (size_t)hi) * 768 + quad * 8;
    segs[1] = pe + (size_t)rel * 768 + quad * 8;
    segs[2] = ce + (size_t)cls * 768 + quad * 8;

    const int ntl = (wave == 0) ? 4 : 3;
    f32x4 acc[4];
#pragma unroll
    for (int u = 0; u < 4; ++u) {
        const int t = wave + 4 * u;
        const int col = t * 16 + n16;
        const float bv = (t < 13 && col < 200) ? bias[col] : 0.0f;
        acc[u] = (f32x4){bv, bv, bv, bv};
    }

    for (int s = 0; s < 3; ++s) {
        const float* ap = segs[s];
#pragma unroll 2
        for (int kk = 0; kk < 768; kk += 32) {
            short8 afr = pack8(*(const f32x4*)(ap + kk), *(const f32x4*)(ap + kk + 4));
#pragma unroll
            for (int u = 0; u < 4; ++u) {
                if (u < ntl) {
                    const int t = wave + 4 * u;
                    const int row = t * 16 + n16;
                    short8 bfr = {0, 0, 0, 0, 0, 0, 0, 0};
                    if (row < 200) {
                        const float* qp = Wf + (size_t)row * 2304 + s * 768 + kk + quad * 8;
                        bfr = pack8(*(const f32x4*)qp, *(const f32x4*)(qp + 4));
                    }
                    acc[u] = __builtin_amdgcn_mfma_f32_16x16x32_bf16(afr, bfr, acc[u], 0, 0, 0);
                }
            }
        }
    }

    const int rbase = blockIdx.x * 16 + quad * 4;
#pragma unroll
    for (int u = 0; u < 4; ++u) {
        const int t = wave + 4 * u;
        if (t < 13) {
            const int col = t * 16 + n16;
            if (col < 200) {
#pragma unroll
                for (int r = 0; r < 4; ++r)
                    out[(size_t)(rbase + r) * 200 + col] = acc[u][r];
            }
        }
    }
}

// ---------------------------------------------------------------------------
extern "C" void kernel_launch(void* const* d_in, const int* in_sizes, int n_in,
                              void* d_out, int out_size, void* d_ws, size_t ws_size,
                              hipStream_t stream) {
    const float* seq  = (const float*)d_in[0];
    const float* pe   = (const float*)d_in[1];
    const float* ce   = (const float*)d_in[2];
    const float* W    = (const float*)d_in[3];
    const float* bias = (const float*)d_in[4];
    const int* head   = (const int*)d_in[5];
    const int* frame  = (const int*)d_in[6];
    const int* pos    = (const int*)d_in[7];
    float* out = (float*)d_out;

    if (d_ws != nullptr && ws_size >= (size_t)WS_NEED_B) {
        unsigned short* ws = (unsigned short*)d_ws;
        void* kargs[] = {(void*)&ws, (void*)&seq, (void*)&pe, (void*)&ce,
                         (void*)&W, (void*)&bias, (void*)&head, (void*)&frame,
                         (void*)&pos, (void*)&out};
        hipError_t e = hipLaunchCooperativeKernel((const void*)fused_kernel,
                                                  dim3(GRID), dim3(512),
                                                  kargs, 0, stream);
        if (e != hipSuccess) {
            // classic two-dispatch path (same math)
            prep_kernel<<<NLOG + (NPACK + 511) / 512, 512, 0, stream>>>(
                pe, ce, W, bias, ws);
            gemm_kernel<<<GRID, 512, 0, stream>>>(ws, seq, head, frame, pos, out);
        }
    } else {
        gemm_fallback<<<1024, 256, 0, stream>>>(seq, pe, ce, W, bias, head,
                                                frame, pos, out);
    }
}

// Round 5
// 125.004 us; speedup vs baseline: 2.3324x; 2.3324x over previous
//
#include <hip/hip_runtime.h>
#include <stdint.h>

// Bert4Argument R12: out = seq·W1 (gathered K=768 GEMM)
//                        + pe_logits[l-pos+256]        (precomputed 528x208)
//                        + ce_logits[l==pos?frame:0]   (precomputed 208x208, bias folded)
// R11 post-mortem: cooperative fusion pathological (186us, all pipes idle) -> reverted.
// R12 = R10 structure + pipelined gemm K-loop:
//   K-chunk 64, 12 chunks, double-buffered LDS (A 2x4KB, B 2x26KB = 60KB),
//   stage(c+1) issued BEFORE compute(c), ONE barrier per chunk (T3 minimum pattern).
//   XCD swizzle: mblk=(bid&7)*64+(bid>>3) -> all 8 blocks of a batch on one XCD
//   (head-gather dedup in L2, predicted seq fetch 50->33 MB).

typedef __attribute__((ext_vector_type(8))) short short8;
typedef __attribute__((ext_vector_type(4))) float f32x4;

#define AS1 __attribute__((address_space(1)))
#define AS3 __attribute__((address_space(3)))

// ---- workspace layout ----
// Wp bf16, 13 tiles x [kb8 0..95][n16][8] = 159744 shorts (319488 B)
// pe_logits f32 [528][208] at float off 79872
// ce_logits f32 [208][208] at float off 189696 (bias folded)
#define TILE_STRIDE 12288     // shorts per n-tile (96*16*8)
#define NT         13
#define NPE_RT     33         // 33*16 = 528 rows cover 513
#define NCE_RT     13         // 13*16 = 208 rows cover 201
#define NLOG      ((NPE_RT + NCE_RT) * NT)   // 598 logits tiles
#define NPACK      19968      // pack thread-units
#define PEL_OFF_F  79872
#define CEL_OFF_F  189696
#define WS_NEED_B  931840

__device__ __forceinline__ unsigned short f2bf(float f) {
    union { float f; unsigned int u; } v; v.f = f;
    unsigned int u = v.u;
    return (unsigned short)((u + 0x7fffu + ((u >> 16) & 1u)) >> 16);
}

__device__ __forceinline__ short8 pack8(f32x4 a, f32x4 b) {
    short8 r;
    r[0] = (short)f2bf(a.x); r[1] = (short)f2bf(a.y);
    r[2] = (short)f2bf(a.z); r[3] = (short)f2bf(a.w);
    r[4] = (short)f2bf(b.x); r[5] = (short)f2bf(b.y);
    r[6] = (short)f2bf(b.z); r[7] = (short)f2bf(b.w);
    return r;
}

__device__ __forceinline__ void dma16(const unsigned short* g, AS3 unsigned short* l) {
    __builtin_amdgcn_global_load_lds((AS1 const unsigned int*)g,
                                     (AS3 unsigned int*)l, 16, 0, 0);
}

// ---------------------------------------------------------------------------
// prep: blocks [0,598): logits. Block = one 16x16 output tile (rowtile x ntile).
//       8 waves K-split 96 each (3 steps of 32), LDS reduce, wave 0 writes.
//       blocks [598,637): pack W[:,0:768] f32 -> bf16 13-tile layout (rows>=200 zero).
// ---------------------------------------------------------------------------
__global__ __launch_bounds__(512) void prep_kernel(
    const float* __restrict__ pe,
    const float* __restrict__ ce,
    const float* __restrict__ W,
    const float* __restrict__ bias,
    unsigned short* __restrict__ ws)
{
    __shared__ float red[2048];

    if (blockIdx.x >= NLOG) {
        // ---- W pack: g = ((t*96 + kb8)*16 + n), k-range [0,768) ----
        const int g   = (blockIdx.x - NLOG) * 512 + threadIdx.x;   // < 19968 exact
        const int n   = g & 15;
        const int kb8 = (g >> 4) % 96;
        const int t   = g / 1536;
        const int row = t * 16 + n;
        const int col = kb8 * 8;
        f32x4 a = {0.f, 0.f, 0.f, 0.f}, b = {0.f, 0.f, 0.f, 0.f};
        if (row < 200) {
            const float* p = W + (size_t)row * 2304 + col;
            a = *(const f32x4*)p;
            b = *(const f32x4*)(p + 4);
        }
        *(short8*)(ws + (size_t)g * 8) = pack8(a, b);
        return;
    }

    // ---- logits ----
    const int bb   = blockIdx.x;
    const int w    = threadIdx.x >> 6;
    const int lane = threadIdx.x & 63;
    const int n16  = lane & 15;
    const int quad = lane >> 4;

    float* wsF = (float*)ws;
    int rowtile, t, nrows, koff;
    const float* A;
    float* outL;
    bool isCe;
    if (bb < NPE_RT * NT) {
        isCe = false; rowtile = bb / NT; t = bb % NT;
        nrows = 513; koff = 768;  A = pe; outL = wsF + PEL_OFF_F;
    } else {
        const int b2 = bb - NPE_RT * NT;
        isCe = true;  rowtile = b2 / NT; t = b2 % NT;
        nrows = 201; koff = 1536; A = ce; outL = wsF + CEL_OFF_F;
    }

    int arow = rowtile * 16 + n16;
    if (arow >= nrows) arow = nrows - 1;            // clamped rows never written
    const float* abase = A + (size_t)arow * 768 + w * 96 + quad * 8;

    const int col  = t * 16 + n16;                  // cols >= 200 junk, never read
    const int wrow = (col < 200) ? col : 0;
    const float* wbase = W + (size_t)wrow * 2304 + koff + w * 96 + quad * 8;

    // all 12 loads issued before any use: one latency round-trip
    f32x4 av0[3], av1[3], wv0[3], wv1[3];
#pragma unroll
    for (int ks = 0; ks < 3; ++ks) {
        av0[ks] = *(const f32x4*)(abase + ks * 32);
        av1[ks] = *(const f32x4*)(abase + ks * 32 + 4);
        wv0[ks] = *(const f32x4*)(wbase + ks * 32);
        wv1[ks] = *(const f32x4*)(wbase + ks * 32 + 4);
    }
    f32x4 acc = (f32x4){0.f, 0.f, 0.f, 0.f};
#pragma unroll
    for (int ks = 0; ks < 3; ++ks)
        acc = __builtin_amdgcn_mfma_f32_16x16x32_bf16(
            pack8(av0[ks], av1[ks]), pack8(wv0[ks], wv1[ks]), acc, 0, 0, 0);

#pragma unroll
    for (int r = 0; r < 4; ++r)
        red[w * 256 + lane * 4 + r] = acc[r];
    __syncthreads();
    if (threadIdx.x < 64) {
        const float bv = (isCe && col < 200) ? bias[col] : 0.0f;
#pragma unroll
        for (int r = 0; r < 4; ++r) {
            float s = 0.f;
#pragma unroll
            for (int ww = 0; ww < 8; ++ww)
                s += red[ww * 256 + lane * 4 + r];
            const int row = rowtile * 16 + quad * 4 + r;
            if (row < nrows)
                outL[(size_t)row * 208 + col] = s + bv;
        }
    }
}

// ---------------------------------------------------------------------------
// Main GEMM: seq-part only. K=768 as 12 chunks of 64, double-buffered.
// grid 512 x 512 thr, mblk = XCD-swizzled blockIdx: (bid&7)*64 + (bid>>3)
// -> batch i's 8 blocks on one XCD (L2 gather dedup).
// LDS 60 KB (shorts): A buf0 @0, A buf1 @2048 (4 slabs x 512 each);
//                     B buf0 @4096, B buf1 @17408 (13 tiles x 1024 each).
// Staging per chunk: waves 4..7 stage A slab (sfm=w&1, sks=(w>>1)&1):
//   2 f32x4 gathered loads -> pack8 -> one ds_write_b128.
// B: 26 dma16 units (t = un>>1, half = un&1) over all 8 waves.
// Pipeline (one barrier per chunk): issue stage(c+1) BEFORE compute(c).
// Compute: wave p=w&1 m-frag, q=w>>1 tiles q+4u (u<4, t<13); 2 ks x mfma.
// Epilogue: + pe_logits[rel,col] + ce_logits[cls,col] (bias inside), write f32.
// ---------------------------------------------------------------------------
__global__ __launch_bounds__(512, 4) void gemm_kernel(
    const unsigned short* __restrict__ ws,
    const float* __restrict__ seq,
    const int*   __restrict__ head,
    const int*   __restrict__ frame,
    const int*   __restrict__ pos,
    float* __restrict__ out)
{
    __shared__ unsigned short lds[30720];   // 61440 B

    const unsigned short* Wp = ws;
    const float* wsF = (const float*)ws;
    const float* peL = wsF + PEL_OFF_F;
    const float* ceL = wsF + CEL_OFF_F;

    const int tid  = threadIdx.x;
    const int wave = tid >> 6;
    const int lane = tid & 63;
    const int n16  = lane & 15;
    const int quad = lane >> 4;

    // XCD swizzle: 8 consecutive mblk (one batch) -> same XCD
    const int mblk = ((blockIdx.x & 7) << 6) | (blockIdx.x >> 3);

    const int i       = mblk >> 3;
    const int pos_i   = pos[i];
    const int frame_i = frame[i];

    // ---- A staging (waves 4..7): slab (sfm, sks) ----
    const bool aStg = (wave >= 4);
    const int sfm = wave & 1;
    const int sks = (wave >> 1) & 1;
    const float* aP = nullptr;
    if (aStg) {
        const int srow = mblk * 32 + sfm * 16 + n16;
        const int hi   = head[srow];
        aP = seq + ((size_t)i * 256 + hi) * 768 + quad * 8;
    }
    unsigned short* aW0 = lds + (sfm * 2 + sks) * 512 + lane * 8;
    unsigned short* aW1 = aW0 + 2048;

    // ---- compute partition: p = m-frag, q -> tiles q+4u ----
    const int p = wave & 1;
    const int q = wave >> 1;
    const unsigned short* aR0 = lds + p * 1024 + lane * 8;          // buf0, +ks*512
    const unsigned short* aR1 = aR0 + 2048;                          // buf1
    const unsigned short* bR0[4];
    const unsigned short* bR1[4];
    bool uok[4];
#pragma unroll
    for (int u = 0; u < 4; ++u) {
        const int t = q + 4 * u;
        uok[u] = (t < NT);
        const int off = (uok[u] ? t : 0) * 1024 + quad * 128 + n16 * 8;
        bR0[u] = lds + 4096 + off;
        bR1[u] = lds + 17408 + off;
    }

    f32x4 acc[4];
#pragma unroll
    for (int u = 0; u < 4; ++u)
        acc[u] = (f32x4){0.f, 0.f, 0.f, 0.f};

    f32x4 a0 = {0,0,0,0}, a1 = {0,0,0,0};

    // ---- prologue: stage chunk 0 -> buf0 ----
    if (aStg) {
        a0 = *(const f32x4*)(aP + sks * 32);
        a1 = *(const f32x4*)(aP + sks * 32 + 4);
    }
#pragma unroll
    for (int un = wave; un < 26; un += 8) {
        const int t = un >> 1, hf = un & 1;
        dma16(Wp + (size_t)t * TILE_STRIDE + hf * 512 + lane * 8,
              (AS3 unsigned short*)lds + 4096 + t * 1024 + hf * 512 + lane * 8);
    }
    if (aStg) *(short8*)aW0 = pack8(a0, a1);
    __syncthreads();

#define COMPUTE(AR, BR)                                                        \
    {                                                                          \
        _Pragma("unroll")                                                      \
        for (int ks = 0; ks < 2; ++ks) {                                       \
            short8 af = *(const short8*)((AR) + ks * 512);                     \
            _Pragma("unroll")                                                  \
            for (int u = 0; u < 4; ++u) {                                      \
                if (uok[u]) {                                                  \
                    short8 bf = *(const short8*)((BR)[u] + ks * 512);          \
                    acc[u] = __builtin_amdgcn_mfma_f32_16x16x32_bf16(          \
                        af, bf, acc[u], 0, 0, 0);                              \
                }                                                              \
            }                                                                  \
        }                                                                      \
    }

    for (int cp = 0; cp < 6; ++cp) {
        const int c0 = 2 * cp, c1 = c0 + 1;
        // ---- even: stage c1 -> buf1 (issue first), compute c0 on buf0 ----
        if (aStg) {
            a0 = *(const f32x4*)(aP + c1 * 64 + sks * 32);
            a1 = *(const f32x4*)(aP + c1 * 64 + sks * 32 + 4);
        }
#pragma unroll
        for (int un = wave; un < 26; un += 8) {
            const int t = un >> 1, hf = un & 1;
            dma16(Wp + (size_t)t * TILE_STRIDE + c1 * 1024 + hf * 512 + lane * 8,
                  (AS3 unsigned short*)lds + 17408 + t * 1024 + hf * 512 + lane * 8);
        }
        COMPUTE(aR0, bR0);
        if (aStg) *(short8*)aW1 = pack8(a0, a1);
        __syncthreads();

        // ---- odd: stage c0+2 -> buf0 (if any), compute c1 on buf1 ----
        if (cp < 5) {
            if (aStg) {
                a0 = *(const f32x4*)(aP + (c0 + 2) * 64 + sks * 32);
                a1 = *(const f32x4*)(aP + (c0 + 2) * 64 + sks * 32 + 4);
            }
#pragma unroll
            for (int un = wave; un < 26; un += 8) {
                const int t = un >> 1, hf = un & 1;
                dma16(Wp + (size_t)t * TILE_STRIDE + (c0 + 2) * 1024 + hf * 512 + lane * 8,
                      (AS3 unsigned short*)lds + 4096 + t * 1024 + hf * 512 + lane * 8);
            }
            COMPUTE(aR1, bR1);
            if (aStg) *(short8*)aW0 = pack8(a0, a1);
            __syncthreads();
        } else {
            COMPUTE(aR1, bR1);
        }
    }
#undef COMPUTE

    // epilogue: C/D col = lane&15, row = quad*4 + r; add gathered logits
    const int rbase = mblk * 32 + p * 16 + quad * 4;
#pragma unroll
    for (int u = 0; u < 4; ++u) {
        if (uok[u]) {
            const int col = (q + 4 * u) * 16 + n16;
            if (col < 200) {
#pragma unroll
                for (int r = 0; r < 4; ++r) {
                    const int row = rbase + r;
                    const int l   = row & 255;
                    const int rel = l - pos_i + 256;
                    const int cls = (l == pos_i) ? frame_i : 0;
                    out[(size_t)row * 200 + col] =
                        acc[u][r] + peL[(size_t)rel * 208 + col]
                                  + ceL[(size_t)cls * 208 + col];
                }
            }
        }
    }
}

// ---------------------------------------------------------------------------
// Fallback (no workspace): slow but correct, f32 W converted inline.
// ---------------------------------------------------------------------------
__global__ __launch_bounds__(256) void gemm_fallback(
    const float* __restrict__ seq, const float* __restrict__ pe,
    const float* __restrict__ ce, const float* __restrict__ Wf,
    const float* __restrict__ bias, const int* __restrict__ head,
    const int* __restrict__ frame, const int* __restrict__ pos,
    float* __restrict__ out)
{
    const int tid  = threadIdx.x;
    const int wave = tid >> 6;
    const int lane = tid & 63;
    const int n16  = lane & 15;
    const int quad = lane >> 4;

    const int mrow  = blockIdx.x * 16 + n16;
    const int i     = mrow >> 8;
    const int j     = mrow & 255;
    const int pos_i = pos[i];
    const int hi    = head[mrow];
    const int rel   = j - pos_i + 256;
    const int cls   = (j == pos_i) ? frame[i] : 0;

    const float* segs[3];
    segs[0] = seq + ((size_t)i * 256 + (size_t)hi) * 768 + quad * 8;
    segs[1] = pe + (size_t)rel * 768 + quad * 8;
    segs[2] = ce + (size_t)cls * 768 + quad * 8;

    const int ntl = (wave == 0) ? 4 : 3;
    f32x4 acc[4];
#pragma unroll
    for (int u = 0; u < 4; ++u) {
        const int t = wave + 4 * u;
        const int col = t * 16 + n16;
        const float bv = (t < 13 && col < 200) ? bias[col] : 0.0f;
        acc[u] = (f32x4){bv, bv, bv, bv};
    }

    for (int s = 0; s < 3; ++s) {
        const float* ap = segs[s];
#pragma unroll 2
        for (int kk = 0; kk < 768; kk += 32) {
            short8 afr = pack8(*(const f32x4*)(ap + kk), *(const f32x4*)(ap + kk + 4));
#pragma unroll
            for (int u = 0; u < 4; ++u) {
                if (u < ntl) {
                    const int t = wave + 4 * u;
                    const int row = t * 16 + n16;
                    short8 bfr = {0, 0, 0, 0, 0, 0, 0, 0};
                    if (row < 200) {
                        const float* qp = Wf + (size_t)row * 2304 + s * 768 + kk + quad * 8;
                        bfr = pack8(*(const f32x4*)qp, *(const f32x4*)(qp + 4));
                    }
                    acc[u] = __builtin_amdgcn_mfma_f32_16x16x32_bf16(afr, bfr, acc[u], 0, 0, 0);
                }
            }
        }
    }

    const int rbase = blockIdx.x * 16 + quad * 4;
#pragma unroll
    for (int u = 0; u < 4; ++u) {
        const int t = wave + 4 * u;
        if (t < 13) {
            const int col = t * 16 + n16;
            if (col < 200) {
#pragma unroll
                for (int r = 0; r < 4; ++r)
                    out[(size_t)(rbase + r) * 200 + col] = acc[u][r];
            }
        }
    }
}

// ---------------------------------------------------------------------------
extern "C" void kernel_launch(void* const* d_in, const int* in_sizes, int n_in,
                              void* d_out, int out_size, void* d_ws, size_t ws_size,
                              hipStream_t stream) {
    const float* seq  = (const float*)d_in[0];
    const float* pe   = (const float*)d_in[1];
    const float* ce   = (const float*)d_in[2];
    const float* W    = (const float*)d_in[3];
    const float* bias = (const float*)d_in[4];
    const int* head   = (const int*)d_in[5];
    const int* frame  = (const int*)d_in[6];
    const int* pos    = (const int*)d_in[7];
    float* out = (float*)d_out;

    if (d_ws != nullptr && ws_size >= (size_t)WS_NEED_B) {
        unsigned short* ws = (unsigned short*)d_ws;
        prep_kernel<<<NLOG + (NPACK + 511) / 512, 512, 0, stream>>>(
            pe, ce, W, bias, ws);
        gemm_kernel<<<512, 512, 0, stream>>>(ws, seq, head, frame, pos, out);
    } else {
        gemm_fallback<<<1024, 256, 0, stream>>>(seq, pe, ce, W, bias, head,
                                                frame, pos, out);
    }
}